// Round 2
// baseline (825.410 us; speedup 1.0000x reference)
//
#include <hip/hip_runtime.h>
#include <math.h>

#define HW 4096

typedef unsigned short ushort_t;
typedef short v8s __attribute__((ext_vector_type(8)));
typedef float v4f __attribute__((ext_vector_type(4)));

__device__ __forceinline__ float bf2f(ushort_t u) {
    union { unsigned int i; float f; } v; v.i = ((unsigned int)u) << 16; return v.f;
}
__device__ __forceinline__ ushort_t f2bf(float f) {
    unsigned int x = __float_as_uint(f);
    x += 0x7fffu + ((x >> 16) & 1u);   // RNE
    return (ushort_t)(x >> 16);
}

// ---------------- per-channel constants -------------------------------------
// cbuf layout (floats): [0]=sE [256]=cE [512]=s1 [768]=c1 [1024]=s2 [1280]=c2
__global__ __launch_bounds__(256) void k_consts(
    const float* eg, const float* ebt, const float* em, const float* ev,
    const float* fb,
    const float* g1, const float* b1, const float* m1, const float* v1,
    const float* balb,
    const float* g2, const float* b2, const float* m2, const float* v2,
    float* cbuf)
{
    int c = threadIdx.x;
    float iE = eg[c] * rsqrtf(ev[c] + 1e-5f);
    cbuf[c]       = iE;
    cbuf[256 + c] = ebt[c] - em[c] * iE;
    float i1 = g1[c] * rsqrtf(v1[c] + 1e-5f);
    cbuf[512 + c] = i1;
    cbuf[768 + c] = b1[c] - m1[c] * i1 + fb[c] * i1;
    float i2 = g2[c] * rsqrtf(v2[c] + 1e-5f);
    cbuf[1024 + c] = i2;
    cbuf[1280 + c] = b2[c] - m2[c] * i2 + balb[c] * i2;
}

// ---------------- bf16 copies of shared weights -----------------------------
// fusw2b[o][c] = bf16(fusion_w[o][256+c]); balwb[o][c] = bf16(balance_w[o][c])
__global__ __launch_bounds__(256) void k_wcopy(const float* fusw, const float* balw,
                                               ushort_t* fusw2b, ushort_t* balwb)
{
    int o = blockIdx.x, t = threadIdx.x;
    fusw2b[o * 256 + t] = f2bf(fusw[o * 512 + 256 + t]);
    balwb[o * 256 + t]  = f2bf(balw[o * 256 + t]);
}

// ---------------- SE avg pool ----------------------------------------------
__global__ __launch_bounds__(256) void k_avg(const float* x, float* avg)
{
    int bc = blockIdx.x;
    int t = threadIdx.x;
    const float4* pv = (const float4*)(x + (size_t)bc * HW);
    float s = 0.f;
    #pragma unroll
    for (int q = 0; q < 4; ++q) {
        float4 v = pv[t + q * 256];
        s += v.x + v.y + v.z + v.w;
    }
    #pragma unroll
    for (int off = 32; off > 0; off >>= 1) s += __shfl_down(s, off, 64);
    __shared__ float red[4];
    if ((t & 63) == 0) red[t >> 6] = s;
    __syncthreads();
    if (t == 0) avg[bc] = (red[0] + red[1] + red[2] + red[3]) * (1.0f / HW);
}

// ---------------- SE MLP + fold att into fusion_w[:, :256] (bf16) -----------
__global__ __launch_bounds__(256) void k_sefold(const float* avg, const float* fc1,
                                                const float* fc2, const float* fusw,
                                                ushort_t* w1b)
{
    int b = blockIdx.x, t = threadIdx.x;
    __shared__ float av[256];
    __shared__ float hid[16];
    av[t] = avg[b * 256 + t];
    __syncthreads();
    if (t < 16) {
        float h = 0.f;
        for (int c = 0; c < 256; ++c) h += av[c] * fc1[t * 256 + c];
        hid[t] = h > 0.f ? h : 0.f;
    }
    __syncthreads();
    float a = 0.f;
    #pragma unroll
    for (int j = 0; j < 16; ++j) a += hid[j] * fc2[t * 16 + j];
    float att = 1.0f / (1.0f + expf(-a));
    ushort_t* wout = w1b + (size_t)b * 65536;
    for (int o = 0; o < 256; ++o)
        wout[o * 256 + t] = f2bf(fusw[o * 512 + t] * att);
}

// ---------------- edge depthwise 3x3 + BN + relu (NCHW, fp32->bf16) ---------
__global__ __launch_bounds__(256) void k_edge(const float* x, const float* ew,
                                              const float* cbuf, ushort_t* et)
{
    int bc = blockIdx.x;
    int c = bc & 255;
    const float* px = x + (size_t)bc * HW;
    ushort_t* pe = et + (size_t)bc * HW;
    float wt[9];
    #pragma unroll
    for (int k = 0; k < 9; ++k) wt[k] = ew[c * 9 + k];
    float sE = cbuf[c], cE = cbuf[256 + c];
    int t = threadIdx.x;
    #pragma unroll 1
    for (int i = 0; i < 16; ++i) {
        int hw = t + i * 256;
        int h = hw >> 6, w = hw & 63;
        float acc = 0.f;
        #pragma unroll
        for (int dh = -1; dh <= 1; ++dh) {
            int hh = h + dh;
            if (hh < 0 || hh > 63) continue;
            #pragma unroll
            for (int dw = -1; dw <= 1; ++dw) {
                int w2 = w + dw;
                if (w2 < 0 || w2 > 63) continue;
                acc += px[hh * 64 + w2] * wt[(dh + 1) * 3 + (dw + 1)];
            }
        }
        float v = acc * sE + cE;
        pe[hw] = f2bf(v > 0.f ? v : 0.f);
    }
}

// ---------------- GEMM1: t1[b][hw][o] = bn1(W1b.x + W2.edge + fb) -----------
// MFMA 16x16x32 bf16; tile 128(m=hw) x 128(n=o) x 64(k=c); 4 waves 2x2.
// A staged ->LDS[m][k] with XOR group-swizzle (k-group ^ (m&7) ^ ((m>>3)&7)).
__global__ __launch_bounds__(256) void k_gemm1(const float* x, const ushort_t* et,
                                               const ushort_t* w1b, const ushort_t* fusw2b,
                                               const float* cbuf, ushort_t* t1)
{
    __shared__ ushort_t At[128 * 64];
    int b = blockIdx.z;
    int hw0 = blockIdx.x * 128;
    int nb = blockIdx.y;
    int t = threadIdx.x;
    int lane = t & 63, wv = t >> 6;
    int quad = lane >> 4, l16 = lane & 15;
    int wr = wv >> 1, wc = wv & 1;

    v4f acc[4][4];
    #pragma unroll
    for (int i = 0; i < 4; ++i)
        #pragma unroll
        for (int j = 0; j < 4; ++j) acc[i][j] = (v4f){0.f, 0.f, 0.f, 0.f};

    int chunk = t & 15;   // hw chunk of 8
    int cr0 = t >> 4;     // 0..15

    int oo[4];
    const ushort_t* rowA[4];  // w1b rows (k<256)
    const ushort_t* rowB[4];  // fusw2b rows (k>=256)
    #pragma unroll
    for (int nt = 0; nt < 4; ++nt) {
        int o = nb * 128 + wc * 64 + nt * 16 + l16;
        oo[nt] = o;
        rowA[nt] = w1b + ((size_t)(b * 256 + o)) * 256;
        rowB[nt] = fusw2b + (size_t)o * 256;
    }

    for (int kb = 0; kb < 8; ++kb) {
        __syncthreads();
        #pragma unroll 1
        for (int cr = 0; cr < 4; ++cr) {
            int c_row = cr0 + cr * 16;
            ushort_t e[8];
            if (kb < 4) {
                const float* p = x + ((size_t)b * 256 + (size_t)(kb * 64 + c_row)) * HW
                                 + hw0 + chunk * 8;
                float4 v0 = *(const float4*)p;
                float4 v1 = *(const float4*)(p + 4);
                e[0] = f2bf(v0.x); e[1] = f2bf(v0.y); e[2] = f2bf(v0.z); e[3] = f2bf(v0.w);
                e[4] = f2bf(v1.x); e[5] = f2bf(v1.y); e[6] = f2bf(v1.z); e[7] = f2bf(v1.w);
            } else {
                const ushort_t* p = et + ((size_t)b * 256 + (size_t)((kb - 4) * 64 + c_row)) * HW
                                    + hw0 + chunk * 8;
                uint4 v = *(const uint4*)p;
                unsigned int wd[4] = { v.x, v.y, v.z, v.w };
                #pragma unroll
                for (int i = 0; i < 8; ++i)
                    e[i] = (i & 1) ? (ushort_t)(wd[i >> 1] >> 16) : (ushort_t)(wd[i >> 1] & 0xffff);
            }
            int gb = c_row >> 3, klo = c_row & 7;
            #pragma unroll
            for (int i = 0; i < 8; ++i) {
                int hwl = chunk * 8 + i;
                int g = gb ^ i ^ (chunk & 7);
                At[hwl * 64 + g * 8 + klo] = e[i];
            }
        }
        __syncthreads();
        #pragma unroll
        for (int ks = 0; ks < 64; ks += 32) {
            int kk = ks + quad * 8;
            int kg = kb * 64 + kk;
            v8s bfr[4], afr[4];
            #pragma unroll
            for (int nt = 0; nt < 4; ++nt) {
                const ushort_t* p = (kg < 256) ? (rowA[nt] + kg) : (rowB[nt] + (kg - 256));
                bfr[nt] = *(const v8s*)p;
            }
            #pragma unroll
            for (int mt = 0; mt < 4; ++mt) {
                int ml = wr * 64 + mt * 16 + l16;
                int g = (kk >> 3) ^ (ml & 7) ^ ((ml >> 3) & 7);
                afr[mt] = *(const v8s*)(&At[ml * 64 + g * 8]);
            }
            #pragma unroll
            for (int mt = 0; mt < 4; ++mt)
                #pragma unroll
                for (int nt = 0; nt < 4; ++nt)
                    acc[mt][nt] = __builtin_amdgcn_mfma_f32_16x16x32_bf16(
                        afr[mt], bfr[nt], acc[mt][nt], 0, 0, 0);
        }
    }
    #pragma unroll
    for (int nt = 0; nt < 4; ++nt) {
        int o = oo[nt];
        float s1 = cbuf[512 + o], c1 = cbuf[768 + o];
        #pragma unroll
        for (int mt = 0; mt < 4; ++mt)
            #pragma unroll
            for (int r = 0; r < 4; ++r) {
                int m = hw0 + wr * 64 + mt * 16 + quad * 4 + r;
                t1[((size_t)b * HW + m) * 256 + o] = f2bf(acc[mt][nt][r] * s1 + c1);
            }
    }
}

// ---------------- depthwise 3x3 (NHWC bf16, deform_w) -----------------------
__global__ __launch_bounds__(256) void k_dw2(const ushort_t* t1, const float* dfw,
                                             ushort_t* t2)
{
    int bid = blockIdx.x;
    int b = bid >> 6, h = bid & 63;
    int o = threadIdx.x;
    float wt[9];
    #pragma unroll
    for (int k = 0; k < 9; ++k) wt[k] = dfw[o * 9 + k];
    const ushort_t* base = t1 + (size_t)b * HW * 256;
    ushort_t* ob = t2 + ((size_t)b * HW + h * 64) * 256;
    #pragma unroll 1
    for (int w = 0; w < 64; ++w) {
        float acc = 0.f;
        #pragma unroll
        for (int dh = -1; dh <= 1; ++dh) {
            int hh = h + dh;
            if (hh < 0 || hh > 63) continue;
            #pragma unroll
            for (int dw = -1; dw <= 1; ++dw) {
                int w2 = w + dw;
                if (w2 < 0 || w2 > 63) continue;
                acc += bf2f(base[(size_t)(hh * 64 + w2) * 256 + o]) * wt[(dh + 1) * 3 + (dw + 1)];
            }
        }
        ob[w * 256 + o] = f2bf(acc);
    }
}

// ---------------- GEMM2: t3[b][hw][o] = balance_w . t2 (raw) ----------------
__global__ __launch_bounds__(256) void k_gemm2(const ushort_t* t2, const ushort_t* balwb,
                                               ushort_t* t3)
{
    __shared__ ushort_t At[128 * 64];
    int b = blockIdx.z;
    int hw0 = blockIdx.x * 128;
    int nb = blockIdx.y;
    int t = threadIdx.x;
    int lane = t & 63, wv = t >> 6;
    int quad = lane >> 4, l16 = lane & 15;
    int wr = wv >> 1, wc = wv & 1;

    v4f acc[4][4];
    #pragma unroll
    for (int i = 0; i < 4; ++i)
        #pragma unroll
        for (int j = 0; j < 4; ++j) acc[i][j] = (v4f){0.f, 0.f, 0.f, 0.f};

    int oo[4];
    const ushort_t* rowW[4];
    #pragma unroll
    for (int nt = 0; nt < 4; ++nt) {
        int o = nb * 128 + wc * 64 + nt * 16 + l16;
        oo[nt] = o;
        rowW[nt] = balwb + (size_t)o * 256;
    }

    for (int kb = 0; kb < 4; ++kb) {
        __syncthreads();
        #pragma unroll
        for (int r2 = 0; r2 < 4; ++r2) {
            int id = r2 * 256 + t;
            int m = id >> 3;
            int kc = (id & 7) * 8;
            uint4 v = *(const uint4*)(t2 + ((size_t)b * HW + hw0 + m) * 256 + kb * 64 + kc);
            int g = (kc >> 3) ^ (m & 7) ^ ((m >> 3) & 7);
            *(uint4*)(&At[m * 64 + g * 8]) = v;
        }
        __syncthreads();
        #pragma unroll
        for (int ks = 0; ks < 64; ks += 32) {
            int kk = ks + quad * 8;
            int kg = kb * 64 + kk;
            v8s bfr[4], afr[4];
            #pragma unroll
            for (int nt = 0; nt < 4; ++nt) bfr[nt] = *(const v8s*)(rowW[nt] + kg);
            #pragma unroll
            for (int mt = 0; mt < 4; ++mt) {
                int ml = wr * 64 + mt * 16 + l16;
                int g = (kk >> 3) ^ (ml & 7) ^ ((ml >> 3) & 7);
                afr[mt] = *(const v8s*)(&At[ml * 64 + g * 8]);
            }
            #pragma unroll
            for (int mt = 0; mt < 4; ++mt)
                #pragma unroll
                for (int nt = 0; nt < 4; ++nt)
                    acc[mt][nt] = __builtin_amdgcn_mfma_f32_16x16x32_bf16(
                        afr[mt], bfr[nt], acc[mt][nt], 0, 0, 0);
        }
    }
    #pragma unroll
    for (int nt = 0; nt < 4; ++nt) {
        int o = oo[nt];
        #pragma unroll
        for (int mt = 0; mt < 4; ++mt)
            #pragma unroll
            for (int r = 0; r < 4; ++r) {
                int m = hw0 + wr * 64 + mt * 16 + quad * 4 + r;
                t3[((size_t)b * HW + m) * 256 + o] = f2bf(acc[mt][nt][r]);
            }
    }
}

// ---------------- final: NHWC->NCHW transpose + BN2 + gate by x (fp32) ------
__global__ __launch_bounds__(256) void k_final(const ushort_t* t3, const float* x,
                                               const float* cbuf, float* out)
{
    __shared__ float Lt[64 * 65];
    int bid = blockIdx.x;
    int b = bid >> 8;
    int rem = bid & 255;
    int hw0 = (rem >> 2) * 64;
    int c0 = (rem & 3) * 64;
    int t = threadIdx.x;
    // load: 64hw x 64c bf16, transpose into LDS as [c][hw] fp32
    #pragma unroll
    for (int r = 0; r < 2; ++r) {
        int idx = r * 256 + t;
        int hwl = idx >> 3;       // 0..63
        int cq = idx & 7;         // 8 channels of 8
        uint4 v = *(const uint4*)(t3 + ((size_t)b * HW + hw0 + hwl) * 256 + c0 + cq * 8);
        unsigned int wd[4] = { v.x, v.y, v.z, v.w };
        #pragma unroll
        for (int j = 0; j < 8; ++j) {
            ushort_t u = (j & 1) ? (ushort_t)(wd[j >> 1] >> 16) : (ushort_t)(wd[j >> 1] & 0xffff);
            Lt[(cq * 8 + j) * 65 + hwl] = bf2f(u);
        }
    }
    __syncthreads();
    int hw_l = t & 63;
    int c_l0 = t >> 6;   // 0..3
    #pragma unroll
    for (int j = 0; j < 16; ++j) {
        int c_l = c_l0 * 16 + j;
        int c = c0 + c_l;
        float s2 = cbuf[1024 + c], c2 = cbuf[1280 + c];
        size_t g = ((size_t)b * 256 + c) * HW + hw0 + hw_l;
        float xv = x[g];
        out[g] = (Lt[c_l * 65 + hw_l] * s2 + c2) * xv;
    }
}

extern "C" void kernel_launch(void* const* d_in, const int* in_sizes, int n_in,
                              void* d_out, int out_size, void* d_ws, size_t ws_size,
                              hipStream_t stream)
{
    const float* x    = (const float*)d_in[0];
    const float* ew   = (const float*)d_in[1];
    const float* eg   = (const float*)d_in[2];
    const float* ebt  = (const float*)d_in[3];
    const float* em   = (const float*)d_in[4];
    const float* ev   = (const float*)d_in[5];
    const float* fc1  = (const float*)d_in[6];
    const float* fc2  = (const float*)d_in[7];
    const float* fusw = (const float*)d_in[8];
    const float* fb   = (const float*)d_in[9];
    const float* g1   = (const float*)d_in[10];
    const float* b1   = (const float*)d_in[11];
    const float* m1   = (const float*)d_in[12];
    const float* v1   = (const float*)d_in[13];
    const float* dfw  = (const float*)d_in[14];
    const float* balw = (const float*)d_in[15];
    const float* balb = (const float*)d_in[16];
    const float* g2   = (const float*)d_in[17];
    const float* b2   = (const float*)d_in[18];
    const float* m2   = (const float*)d_in[19];
    const float* v2   = (const float*)d_in[20];
    float* out = (float*)d_out;

    char* ws = (char*)d_ws;
    // layout (bytes):
    // [0, 64M)        et  bf16 NCHW edge  (reused as t2 NHWC)
    // [64M, 128M)     t1  bf16 NHWC       (reused as t3)
    // [128M, +4M)     w1b bf16 [32][256][256]
    // then fusw2b (128K), balwb (128K), avg (32K), cbuf (6K)
    ushort_t* et     = (ushort_t*)(ws);
    ushort_t* t1     = (ushort_t*)(ws + 67108864);
    ushort_t* t2     = et;
    ushort_t* t3     = t1;
    ushort_t* w1b    = (ushort_t*)(ws + 134217728);
    ushort_t* fusw2b = (ushort_t*)(ws + 138412032);
    ushort_t* balwb  = (ushort_t*)(ws + 138543104);
    float*    avg    = (float*)(ws + 138674176);
    float*    cbuf   = (float*)(ws + 138706944);

    k_consts<<<1, 256, 0, stream>>>(eg, ebt, em, ev, fb, g1, b1, m1, v1,
                                    balb, g2, b2, m2, v2, cbuf);
    k_wcopy<<<256, 256, 0, stream>>>(fusw, balw, fusw2b, balwb);
    k_avg<<<8192, 256, 0, stream>>>(x, avg);
    k_sefold<<<32, 256, 0, stream>>>(avg, fc1, fc2, fusw, w1b);
    k_edge<<<8192, 256, 0, stream>>>(x, ew, cbuf, et);
    k_gemm1<<<dim3(32, 2, 32), 256, 0, stream>>>(x, et, w1b, fusw2b, cbuf, t1);
    k_dw2<<<2048, 256, 0, stream>>>(t1, dfw, t2);
    k_gemm2<<<dim3(32, 2, 32), 256, 0, stream>>>(t2, balwb, t3);
    k_final<<<8192, 256, 0, stream>>>(t3, x, cbuf, out);
}

// Round 3
// 578.051 us; speedup vs baseline: 1.4279x; 1.4279x over previous
//
#include <hip/hip_runtime.h>
#include <math.h>

#define HW 4096

typedef unsigned short ushort_t;
typedef short v8s __attribute__((ext_vector_type(8)));
typedef float v4f __attribute__((ext_vector_type(4)));

__device__ __forceinline__ float bf2f(ushort_t u) {
    union { unsigned int i; float f; } v; v.i = ((unsigned int)u) << 16; return v.f;
}
__device__ __forceinline__ ushort_t f2bf(float f) {
    unsigned int x = __float_as_uint(f);
    x += 0x7fffu + ((x >> 16) & 1u);   // RNE
    return (ushort_t)(x >> 16);
}

// ---------------- per-channel constants -------------------------------------
// cbuf layout (floats): [0]=sE [256]=cE [512]=s1 [768]=c1 [1024]=s2 [1280]=c2
__global__ __launch_bounds__(256) void k_consts(
    const float* eg, const float* ebt, const float* em, const float* ev,
    const float* fb,
    const float* g1, const float* b1, const float* m1, const float* v1,
    const float* balb,
    const float* g2, const float* b2, const float* m2, const float* v2,
    float* cbuf)
{
    int c = threadIdx.x;
    float iE = eg[c] * rsqrtf(ev[c] + 1e-5f);
    cbuf[c]       = iE;
    cbuf[256 + c] = ebt[c] - em[c] * iE;
    float i1 = g1[c] * rsqrtf(v1[c] + 1e-5f);
    cbuf[512 + c] = i1;
    cbuf[768 + c] = b1[c] - m1[c] * i1 + fb[c] * i1;
    float i2 = g2[c] * rsqrtf(v2[c] + 1e-5f);
    cbuf[1024 + c] = i2;
    cbuf[1280 + c] = b2[c] - m2[c] * i2 + balb[c] * i2;
}

// ---------------- bf16 copies of shared weights -----------------------------
__global__ __launch_bounds__(256) void k_wcopy(const float* fusw, const float* balw,
                                               ushort_t* fusw2b, ushort_t* balwb)
{
    int o = blockIdx.x, t = threadIdx.x;
    fusw2b[o * 256 + t] = f2bf(fusw[o * 512 + 256 + t]);
    balwb[o * 256 + t]  = f2bf(balw[o * 256 + t]);
}

// ---------------- edge depthwise 3x3 + BN + relu + fused SE avg pool --------
// Sliding vertical window: thread owns (plane, w); 3 coalesced fp32 loads +
// 9 FMA per output. 4 planes per 256-thread block (1 plane per wave).
__global__ __launch_bounds__(256) void k_edge(const float* x, const float* ew,
                                              const float* cbuf, ushort_t* et,
                                              float* avg)
{
    int bid = blockIdx.x;              // 0..2047
    int b = bid >> 6;
    int cq = bid & 63;
    int t = threadIdx.x;
    int w = t & 63;
    int pl = t >> 6;                   // wave index = plane within block
    int c = cq * 4 + pl;
    const float* px = x + ((size_t)(b * 256 + c)) * HW;
    ushort_t* pe = et + ((size_t)(b * 256 + c)) * HW;
    float wt[9];
    #pragma unroll
    for (int k = 0; k < 9; ++k) wt[k] = ew[c * 9 + k];
    float sE = cbuf[c], cE = cbuf[256 + c];
    bool wl = (w > 0), wr = (w < 63);

    float p0l = 0.f, p0c = 0.f, p0r = 0.f;
    float p1l, p1c, p1r;
    p1c = px[w];
    p1l = wl ? px[w - 1] : 0.f;
    p1r = wr ? px[w + 1] : 0.f;
    float s = 0.f;
    #pragma unroll 4
    for (int h = 0; h < 64; ++h) {
        float p2l, p2c, p2r;
        if (h < 63) {
            const float* row = px + (h + 1) * 64;
            p2c = row[w];
            p2l = wl ? row[w - 1] : 0.f;
            p2r = wr ? row[w + 1] : 0.f;
        } else {
            p2l = p2c = p2r = 0.f;
        }
        float a = p0l * wt[0] + p0c * wt[1] + p0r * wt[2]
                + p1l * wt[3] + p1c * wt[4] + p1r * wt[5]
                + p2l * wt[6] + p2c * wt[7] + p2r * wt[8];
        s += p1c;
        float v = a * sE + cE;
        pe[h * 64 + w] = f2bf(v > 0.f ? v : 0.f);
        p0l = p1l; p0c = p1c; p0r = p1r;
        p1l = p2l; p1c = p2c; p1r = p2r;
    }
    #pragma unroll
    for (int off = 32; off > 0; off >>= 1) s += __shfl_down(s, off, 64);
    if ((t & 63) == 0) avg[b * 256 + c] = s * (1.0f / HW);
}

// ---------------- SE MLP + fold att into fusion_w[:, :256] (bf16) -----------
__global__ __launch_bounds__(256) void k_sefold(const float* avg, const float* fc1,
                                                const float* fc2, const float* fusw,
                                                ushort_t* w1b)
{
    int b = blockIdx.x, t = threadIdx.x;
    __shared__ float av[256];
    __shared__ float hid[16];
    av[t] = avg[b * 256 + t];
    __syncthreads();
    if (t < 16) {
        float h = 0.f;
        for (int c = 0; c < 256; ++c) h += av[c] * fc1[t * 256 + c];
        hid[t] = h > 0.f ? h : 0.f;
    }
    __syncthreads();
    float a = 0.f;
    #pragma unroll
    for (int j = 0; j < 16; ++j) a += hid[j] * fc2[t * 16 + j];
    float att = 1.0f / (1.0f + expf(-a));
    ushort_t* wout = w1b + (size_t)b * 65536;
    for (int o = 0; o < 256; ++o)
        wout[o * 256 + t] = f2bf(fusw[o * 512 + t] * att);
}

// ---------------- GEMM1: t1[b][hw][o] = bn1(W1b.x + W2.edge + fb) -----------
__global__ __launch_bounds__(256) void k_gemm1(const float* x, const ushort_t* et,
                                               const ushort_t* w1b, const ushort_t* fusw2b,
                                               const float* cbuf, ushort_t* t1)
{
    __shared__ ushort_t At[128 * 64];
    int b = blockIdx.z;
    int hw0 = blockIdx.x * 128;
    int nb = blockIdx.y;
    int t = threadIdx.x;
    int lane = t & 63, wv = t >> 6;
    int quad = lane >> 4, l16 = lane & 15;
    int wr = wv >> 1, wc = wv & 1;

    v4f acc[4][4];
    #pragma unroll
    for (int i = 0; i < 4; ++i)
        #pragma unroll
        for (int j = 0; j < 4; ++j) acc[i][j] = (v4f){0.f, 0.f, 0.f, 0.f};

    int chunk = t & 15;
    int cr0 = t >> 4;

    int oo[4];
    const ushort_t* rowA[4];
    const ushort_t* rowB[4];
    #pragma unroll
    for (int nt = 0; nt < 4; ++nt) {
        int o = nb * 128 + wc * 64 + nt * 16 + l16;
        oo[nt] = o;
        rowA[nt] = w1b + ((size_t)(b * 256 + o)) * 256;
        rowB[nt] = fusw2b + (size_t)o * 256;
    }

    for (int kb = 0; kb < 8; ++kb) {
        __syncthreads();
        #pragma unroll 1
        for (int cr = 0; cr < 4; ++cr) {
            int c_row = cr0 + cr * 16;
            ushort_t e[8];
            if (kb < 4) {
                const float* p = x + ((size_t)b * 256 + (size_t)(kb * 64 + c_row)) * HW
                                 + hw0 + chunk * 8;
                float4 v0 = *(const float4*)p;
                float4 v1 = *(const float4*)(p + 4);
                e[0] = f2bf(v0.x); e[1] = f2bf(v0.y); e[2] = f2bf(v0.z); e[3] = f2bf(v0.w);
                e[4] = f2bf(v1.x); e[5] = f2bf(v1.y); e[6] = f2bf(v1.z); e[7] = f2bf(v1.w);
            } else {
                const ushort_t* p = et + ((size_t)b * 256 + (size_t)((kb - 4) * 64 + c_row)) * HW
                                    + hw0 + chunk * 8;
                uint4 v = *(const uint4*)p;
                unsigned int wd[4] = { v.x, v.y, v.z, v.w };
                #pragma unroll
                for (int i = 0; i < 8; ++i)
                    e[i] = (i & 1) ? (ushort_t)(wd[i >> 1] >> 16) : (ushort_t)(wd[i >> 1] & 0xffff);
            }
            int gb = c_row >> 3, klo = c_row & 7;
            #pragma unroll
            for (int i = 0; i < 8; ++i) {
                int hwl = chunk * 8 + i;
                int g = gb ^ i ^ (chunk & 7);
                At[hwl * 64 + g * 8 + klo] = e[i];
            }
        }
        __syncthreads();
        #pragma unroll
        for (int ks = 0; ks < 64; ks += 32) {
            int kk = ks + quad * 8;
            int kg = kb * 64 + kk;
            v8s bfr[4], afr[4];
            #pragma unroll
            for (int nt = 0; nt < 4; ++nt) {
                const ushort_t* p = (kg < 256) ? (rowA[nt] + kg) : (rowB[nt] + (kg - 256));
                bfr[nt] = *(const v8s*)p;
            }
            #pragma unroll
            for (int mt = 0; mt < 4; ++mt) {
                int ml = wr * 64 + mt * 16 + l16;
                int g = (kk >> 3) ^ (ml & 7) ^ ((ml >> 3) & 7);
                afr[mt] = *(const v8s*)(&At[ml * 64 + g * 8]);
            }
            #pragma unroll
            for (int mt = 0; mt < 4; ++mt)
                #pragma unroll
                for (int nt = 0; nt < 4; ++nt)
                    acc[mt][nt] = __builtin_amdgcn_mfma_f32_16x16x32_bf16(
                        afr[mt], bfr[nt], acc[mt][nt], 0, 0, 0);
        }
    }
    #pragma unroll
    for (int nt = 0; nt < 4; ++nt) {
        int o = oo[nt];
        float s1 = cbuf[512 + o], c1 = cbuf[768 + o];
        #pragma unroll
        for (int mt = 0; mt < 4; ++mt)
            #pragma unroll
            for (int r = 0; r < 4; ++r) {
                int m = hw0 + wr * 64 + mt * 16 + quad * 4 + r;
                t1[((size_t)b * HW + m) * 256 + o] = f2bf(acc[mt][nt][r] * s1 + c1);
            }
    }
}

// ---------------- depthwise 3x3 (NHWC bf16) — register-tiled 8ch x 8w -------
// block: 256 thr = 32 ch-groups(8ch) x 8 w-chunks(8w); grid (64 h, 32 b).
__global__ __launch_bounds__(256) void k_dw2(const ushort_t* t1, const float* dfw,
                                             ushort_t* t2)
{
    int h = blockIdx.x;
    int b = blockIdx.y;
    int t = threadIdx.x;
    int cg = t & 31;
    int wc = t >> 5;
    int c0 = cg * 8;
    int w0 = wc * 8;

    float acc[8][8];   // [w][ch]
    #pragma unroll
    for (int w = 0; w < 8; ++w)
        #pragma unroll
        for (int ch = 0; ch < 8; ++ch) acc[w][ch] = 0.f;

    const ushort_t* base = t1 + ((size_t)b * HW) * 256;
    #pragma unroll
    for (int r = 0; r < 3; ++r) {
        int hh = h - 1 + r;
        if (hh < 0 || hh > 63) continue;
        // row-specific weights: 3 taps x 8 ch
        float wtr[3][8];
        #pragma unroll
        for (int d = 0; d < 3; ++d)
            #pragma unroll
            for (int ch = 0; ch < 8; ++ch)
                wtr[d][ch] = dfw[(c0 + ch) * 9 + r * 3 + d];
        const ushort_t* row = base + (size_t)(hh * 64) * 256;
        uint4 rv[10];
        #pragma unroll
        for (int j = 0; j < 10; ++j) {
            int col = w0 - 1 + j;
            if (col >= 0 && col < 64)
                rv[j] = *(const uint4*)(row + (size_t)col * 256 + c0);
            else
                rv[j] = (uint4){0u, 0u, 0u, 0u};
        }
        #pragma unroll
        for (int j = 0; j < 10; ++j) {
            unsigned int wd[4] = { rv[j].x, rv[j].y, rv[j].z, rv[j].w };
            float v[8];
            #pragma unroll
            for (int i = 0; i < 8; ++i)
                v[i] = bf2f((i & 1) ? (ushort_t)(wd[i >> 1] >> 16)
                                    : (ushort_t)(wd[i >> 1] & 0xffff));
            if (j <= 7)
                #pragma unroll
                for (int ch = 0; ch < 8; ++ch) acc[j][ch] += v[ch] * wtr[0][ch];
            if (j >= 1 && j <= 8)
                #pragma unroll
                for (int ch = 0; ch < 8; ++ch) acc[j - 1][ch] += v[ch] * wtr[1][ch];
            if (j >= 2)
                #pragma unroll
                for (int ch = 0; ch < 8; ++ch) acc[j - 2][ch] += v[ch] * wtr[2][ch];
        }
    }
    ushort_t* ob = t2 + ((size_t)b * HW + h * 64 + w0) * 256 + c0;
    #pragma unroll
    for (int w = 0; w < 8; ++w) {
        uint4 ov;
        ov.x = (unsigned int)f2bf(acc[w][0]) | ((unsigned int)f2bf(acc[w][1]) << 16);
        ov.y = (unsigned int)f2bf(acc[w][2]) | ((unsigned int)f2bf(acc[w][3]) << 16);
        ov.z = (unsigned int)f2bf(acc[w][4]) | ((unsigned int)f2bf(acc[w][5]) << 16);
        ov.w = (unsigned int)f2bf(acc[w][6]) | ((unsigned int)f2bf(acc[w][7]) << 16);
        *(uint4*)(ob + (size_t)w * 256) = ov;
    }
}

// ---------------- GEMM2: t3[b][hw][o] = balance_w . t2 (raw) ----------------
__global__ __launch_bounds__(256) void k_gemm2(const ushort_t* t2, const ushort_t* balwb,
                                               ushort_t* t3)
{
    __shared__ ushort_t At[128 * 64];
    int b = blockIdx.z;
    int hw0 = blockIdx.x * 128;
    int nb = blockIdx.y;
    int t = threadIdx.x;
    int lane = t & 63, wv = t >> 6;
    int quad = lane >> 4, l16 = lane & 15;
    int wr = wv >> 1, wc = wv & 1;

    v4f acc[4][4];
    #pragma unroll
    for (int i = 0; i < 4; ++i)
        #pragma unroll
        for (int j = 0; j < 4; ++j) acc[i][j] = (v4f){0.f, 0.f, 0.f, 0.f};

    int oo[4];
    const ushort_t* rowW[4];
    #pragma unroll
    for (int nt = 0; nt < 4; ++nt) {
        int o = nb * 128 + wc * 64 + nt * 16 + l16;
        oo[nt] = o;
        rowW[nt] = balwb + (size_t)o * 256;
    }

    for (int kb = 0; kb < 4; ++kb) {
        __syncthreads();
        #pragma unroll
        for (int r2 = 0; r2 < 4; ++r2) {
            int id = r2 * 256 + t;
            int m = id >> 3;
            int kc = (id & 7) * 8;
            uint4 v = *(const uint4*)(t2 + ((size_t)b * HW + hw0 + m) * 256 + kb * 64 + kc);
            int g = (kc >> 3) ^ (m & 7) ^ ((m >> 3) & 7);
            *(uint4*)(&At[m * 64 + g * 8]) = v;
        }
        __syncthreads();
        #pragma unroll
        for (int ks = 0; ks < 64; ks += 32) {
            int kk = ks + quad * 8;
            int kg = kb * 64 + kk;
            v8s bfr[4], afr[4];
            #pragma unroll
            for (int nt = 0; nt < 4; ++nt) bfr[nt] = *(const v8s*)(rowW[nt] + kg);
            #pragma unroll
            for (int mt = 0; mt < 4; ++mt) {
                int ml = wr * 64 + mt * 16 + l16;
                int g = (kk >> 3) ^ (ml & 7) ^ ((ml >> 3) & 7);
                afr[mt] = *(const v8s*)(&At[ml * 64 + g * 8]);
            }
            #pragma unroll
            for (int mt = 0; mt < 4; ++mt)
                #pragma unroll
                for (int nt = 0; nt < 4; ++nt)
                    acc[mt][nt] = __builtin_amdgcn_mfma_f32_16x16x32_bf16(
                        afr[mt], bfr[nt], acc[mt][nt], 0, 0, 0);
        }
    }
    #pragma unroll
    for (int nt = 0; nt < 4; ++nt) {
        int o = oo[nt];
        #pragma unroll
        for (int mt = 0; mt < 4; ++mt)
            #pragma unroll
            for (int r = 0; r < 4; ++r) {
                int m = hw0 + wr * 64 + mt * 16 + quad * 4 + r;
                t3[((size_t)b * HW + m) * 256 + o] = f2bf(acc[mt][nt][r]);
            }
    }
}

// ---------------- final: NHWC->NCHW transpose + BN2 + gate by x (fp32) ------
__global__ __launch_bounds__(256) void k_final(const ushort_t* t3, const float* x,
                                               const float* cbuf, float* out)
{
    __shared__ float Lt[64 * 65];
    int bid = blockIdx.x;
    int b = bid >> 8;
    int rem = bid & 255;
    int hw0 = (rem >> 2) * 64;
    int c0 = (rem & 3) * 64;
    int t = threadIdx.x;
    #pragma unroll
    for (int r = 0; r < 2; ++r) {
        int idx = r * 256 + t;
        int hwl = idx >> 3;
        int cq = idx & 7;
        uint4 v = *(const uint4*)(t3 + ((size_t)b * HW + hw0 + hwl) * 256 + c0 + cq * 8);
        unsigned int wd[4] = { v.x, v.y, v.z, v.w };
        #pragma unroll
        for (int j = 0; j < 8; ++j) {
            ushort_t u = (j & 1) ? (ushort_t)(wd[j >> 1] >> 16) : (ushort_t)(wd[j >> 1] & 0xffff);
            Lt[(cq * 8 + j) * 65 + hwl] = bf2f(u);
        }
    }
    __syncthreads();
    int hw_l = t & 63;
    int c_l0 = t >> 6;
    #pragma unroll
    for (int j = 0; j < 16; ++j) {
        int c_l = c_l0 * 16 + j;
        int c = c0 + c_l;
        float s2 = cbuf[1024 + c], c2 = cbuf[1280 + c];
        size_t g = ((size_t)b * 256 + c) * HW + hw0 + hw_l;
        float xv = x[g];
        out[g] = (Lt[c_l * 65 + hw_l] * s2 + c2) * xv;
    }
}

extern "C" void kernel_launch(void* const* d_in, const int* in_sizes, int n_in,
                              void* d_out, int out_size, void* d_ws, size_t ws_size,
                              hipStream_t stream)
{
    const float* x    = (const float*)d_in[0];
    const float* ew   = (const float*)d_in[1];
    const float* fc1  = (const float*)d_in[6];
    const float* fc2  = (const float*)d_in[7];
    const float* fusw = (const float*)d_in[8];
    const float* dfw  = (const float*)d_in[14];
    const float* balw = (const float*)d_in[15];
    float* out = (float*)d_out;

    char* ws = (char*)d_ws;
    ushort_t* et     = (ushort_t*)(ws);
    ushort_t* t1     = (ushort_t*)(ws + 67108864);
    ushort_t* t2     = et;
    ushort_t* t3     = t1;
    ushort_t* w1b    = (ushort_t*)(ws + 134217728);
    ushort_t* fusw2b = (ushort_t*)(ws + 138412032);
    ushort_t* balwb  = (ushort_t*)(ws + 138543104);
    float*    avg    = (float*)(ws + 138674176);
    float*    cbuf   = (float*)(ws + 138706944);

    k_consts<<<1, 256, 0, stream>>>((const float*)d_in[2], (const float*)d_in[3],
                                    (const float*)d_in[4], (const float*)d_in[5],
                                    (const float*)d_in[9],
                                    (const float*)d_in[10], (const float*)d_in[11],
                                    (const float*)d_in[12], (const float*)d_in[13],
                                    (const float*)d_in[16],
                                    (const float*)d_in[17], (const float*)d_in[18],
                                    (const float*)d_in[19], (const float*)d_in[20],
                                    cbuf);
    k_wcopy<<<256, 256, 0, stream>>>(fusw, balw, fusw2b, balwb);
    k_edge<<<2048, 256, 0, stream>>>(x, ew, cbuf, et, avg);
    k_sefold<<<32, 256, 0, stream>>>(avg, fc1, fc2, fusw, w1b);
    k_gemm1<<<dim3(32, 2, 32), 256, 0, stream>>>(x, et, w1b, fusw2b, cbuf, t1);
    k_dw2<<<dim3(64, 32), 256, 0, stream>>>(t1, dfw, t2);
    k_gemm2<<<dim3(32, 2, 32), 256, 0, stream>>>(t2, balwb, t3);
    k_final<<<8192, 256, 0, stream>>>(t3, x, cbuf, out);
}